// Round 7
// baseline (444.680 us; speedup 1.0000x reference)
//
#include <hip/hip_runtime.h>

// --- MFMA fp16 LSTM, Round 18: 4 barrier domains/CU, 8 waves/SIMD ---
// Invariant across r12-r17: phase ~8k cyc, VALU-busy ~4.2k, gap ~3.8k.
// Attacked LDS reads (r17: halved, null), write conflicts (r16: worse),
// scheduling (r13/r15: null). Never varied: barrier-domain topology --
// always 2 domains/CU, <=4 waves/SIMD; a domain drains/refills at each
// barrier -> ~50% duty on every pipe. r18: SAME per-CU work as r12 (8192 h,
// 448 MFMA, 160 b128 reads per CU-phase) split into 1024 blocks x 16 batch
// (512 thr, 8 waves, wave = 2 m-tiles x 1 n-tile). 4 domains/CU x 8 waves/
// SIMD (launch_bounds(512,8): 64-VGPR cap; r12 measured exactly 64 with a
// strictly larger per-wave state). Domains desync naturally -> pipes stay
// fed through each domain's barrier drain.
// Phase p: layer1(t=p) reads h0(p),h1(p-1); layer0(t=p+1) reads x(p+1),h0(p);
// 29 barriers. Weights pre-scaled (i/f/o by -log2e, g by +2log2e) -> bare
// exp2; gate math = verified 7-trans form. Planes frag-linear (conflict-free
// b128 reads). All r12-verified index mappings preserved.

typedef _Float16 half8 __attribute__((ext_vector_type(8)));
typedef float floatx4 __attribute__((ext_vector_type(4)));

#define NFRAG 112
#define WS_BIAS_OFF (NFRAG * 1024)
#define K2 2.8853900817779268f      // 2*log2(e)

#if __has_builtin(__builtin_amdgcn_exp2f)
#define EXP2(v) __builtin_amdgcn_exp2f(v)
#else
#define EXP2(v) __expf(0.6931471805599453f * (v))
#endif
#define RCP(v) __builtin_amdgcn_rcpf(v)

__global__ void prep_kernel(const float* __restrict__ Wih0, const float* __restrict__ Whh0,
                            const float* __restrict__ bih0, const float* __restrict__ bhh0,
                            const float* __restrict__ Wih1, const float* __restrict__ Whh1,
                            const float* __restrict__ bih1, const float* __restrict__ bhh1,
                            _Float16* __restrict__ wA, float* __restrict__ wBias) {
    int idx = blockIdx.x * blockDim.x + threadIdx.x;
    if (idx < NFRAG * 512) {
        int f = idx >> 9, slot = idx & 511;
        int lane = slot >> 3, j = slot & 7;
        int mt, kt, layer;
        if (f < 48) { layer = 0; mt = f / 3; kt = f % 3; }
        else        { layer = 1; int f2 = f - 48; mt = f2 >> 2; kt = f2 & 3; }
        int m = mt * 16 + (lane & 15);
        int k = kt * 32 + (lane >> 4) * 8 + j;
        int u = m >> 2, g = m & 3;
        int row = g * 64 + u;
        float v;
        if (layer == 0) {
            if (k < 28)       v = Wih0[row * 28 + k];
            else if (k == 28) v = bih0[row] + bhh0[row];
            else if (k < 32)  v = 0.f;
            else              v = Whh0[row * 64 + (k - 32)];
        } else {
            if (k < 64)       v = Wih1[row * 64 + k];
            else              v = Whh1[row * 64 + (k - 64)];
        }
        float s = (g == 2) ? K2 : -1.4426950408889634f;
        wA[idx] = (_Float16)(v * s);
    } else if (idx < NFRAG * 512 + 256) {
        int m = idx - NFRAG * 512;
        int g = m & 3;
        int row = g * 64 + (m >> 2);
        float s = (g == 2) ? K2 : -1.4426950408889634f;
        wBias[m] = (bih1[row] + bhh1[row]) * s;
    }
}

// Breadth-first N-tile gate batch on PRE-SCALED accs (r12-verified form).
// cn = [c*pg*pi + (eg-1)*pf] / (pf*pg*pi)  (1 rcp); h = (ec-1)/(ec*po+po).
template <int N>
__device__ __forceinline__ void gate_batch(const floatx4* acc, float* c,
                                           _Float16* const* planes, const int* offs) {
    float ei[N], ef[N], eg[N], eo[N];
    #pragma unroll
    for (int i = 0; i < N; ++i) {
        floatx4 a = acc[i];
        ei[i] = EXP2(a[0]);
        ef[i] = EXP2(a[1]);
        eg[i] = EXP2(a[2]);
        eo[i] = EXP2(a[3]);
    }
    float num[N], rd[N], po[N];
    #pragma unroll
    for (int i = 0; i < N; ++i) {
        float pi = 1.0f + ei[i];
        float pf = 1.0f + ef[i];
        float pg = 1.0f + eg[i];
        po[i] = 1.0f + eo[i];
        float m = pg * pi;
        num[i] = c[i] * m + (eg[i] - 1.0f) * pf;
        rd[i]  = RCP(pf * m);
    }
    float ec[N];
    #pragma unroll
    for (int i = 0; i < N; ++i) {
        float cn = num[i] * rd[i];
        c[i] = cn;
        ec[i] = EXP2(K2 * cn);
    }
    #pragma unroll
    for (int i = 0; i < N; ++i) {
        float r2 = RCP(ec[i] * po[i] + po[i]);
        planes[i][offs[i]] = (_Float16)((ec[i] - 1.0f) * r2);
    }
}

__launch_bounds__(512, 8)
__global__ void lstm_mfma(const float* __restrict__ x,
                          const _Float16* __restrict__ wA,
                          const float* __restrict__ wBias,
                          const float* __restrict__ Wlin, const float* __restrict__ blin,
                          float* __restrict__ out) {
    __shared__ __align__(16) _Float16 h0p[2][1024];  // [parity][K64 x n16 frag-linear]
    __shared__ __align__(16) _Float16 h1p[2][1024];
    __shared__ __align__(16) _Float16 xb[2][512];    // [parity][K32 x n16]
    __shared__ float wlin_s[640];
    __shared__ float blin_s[10];

    const int lane = threadIdx.x;
    const int w    = threadIdx.y;      // 0..7
    const int tid  = w * 64 + lane;
    const int quad = lane >> 4;
    const int col  = lane & 15;
    const int l8   = lane * 8;

    // ---- A fragments: wave owns m-tiles MT = 2w+j, units u = MT*4+quad ----
    half8 A0[2][3], A1[2][4];
    floatx4 bias1[2];
    int hwr[2];
    #pragma unroll
    for (int j = 0; j < 2; ++j) {
        const int MT = 2 * w + j;
        #pragma unroll
        for (int kt = 0; kt < 3; ++kt)
            A0[j][kt] = *(const half8*)(wA + (MT * 3 + kt) * 512 + l8);
        #pragma unroll
        for (int kt = 0; kt < 4; ++kt)
            A1[j][kt] = *(const half8*)(wA + (48 + MT * 4 + kt) * 512 + l8);
        const int u = MT * 4 + quad;
        bias1[j] = *(const floatx4*)(wBias + u * 4);
        hwr[j] = (u >> 5) * 512 + (((u >> 3) & 3) * 16 + col) * 8 + (u & 7);
    }

    // ---- x staging: thread covers (k = tid&31, batch col = tid>>5, 0..15) ----
    const int ks = tid & 31;
    const int cs = tid >> 5;
    const bool xvalid = ks < 28;
    const bool xone   = (ks == 28);
    const float* xg = x + (blockIdx.x * 16 + cs) * 784 + ks;
    const int xstg = ((ks >> 3) * 16 + cs) * 8 + (ks & 7);

    // ---- init: zero parity-1 planes, stage x(0) ----
    {
        ((int*)&h0p[1][0])[tid] = 0;
        ((int*)&h1p[1][0])[tid] = 0;
        float xv = xvalid ? xg[0] : 0.f;
        xb[0][xstg] = xone ? (_Float16)1.0f : (_Float16)xv;
    }
    __syncthreads();

    float c0[2] = {0.f, 0.f};
    float c1[2] = {0.f, 0.f};

    for (int p = -1; p <= 27; ++p) {
        const int pr  = p & 1;
        const int pr1 = pr ^ 1;
        const bool doL0 = (p < 27);
        const bool doL1 = (p >= 0);

        // (1) global prefetch x(p+2)
        float xn = 0.f;
        if (p <= 25 && xvalid) xn = xg[(p + 2) * 28];

        // (2) up-front B-frag reads: bx (1) + bh0 (2)
        half8 bx, bh0[2];
        if (doL0) bx = *(const half8*)&xb[pr1][l8];
        #pragma unroll
        for (int kt = 0; kt < 2; ++kt)
            bh0[kt] = *(const half8*)&h0p[pr][kt * 512 + l8];

        // (3) L0 MFMAs + L1 h0-part MFMAs
        floatx4 acc0[2], acc1[2];
        if (doL0) {
            #pragma unroll
            for (int j = 0; j < 2; ++j) {
                acc0[j] = __builtin_amdgcn_mfma_f32_16x16x32_f16(
                              A0[j][0], bx, (floatx4){0.f, 0.f, 0.f, 0.f}, 0, 0, 0);
                #pragma unroll
                for (int kt = 0; kt < 2; ++kt)
                    acc0[j] = __builtin_amdgcn_mfma_f32_16x16x32_f16(
                                  A0[j][kt + 1], bh0[kt], acc0[j], 0, 0, 0);
            }
        }
        if (doL1) {
            #pragma unroll
            for (int j = 0; j < 2; ++j) {
                acc1[j] = bias1[j];
                #pragma unroll
                for (int kt = 0; kt < 2; ++kt)
                    acc1[j] = __builtin_amdgcn_mfma_f32_16x16x32_f16(
                                  A1[j][kt], bh0[kt], acc1[j], 0, 0, 0);
            }
            // (4) bh1 reads then L1 tail MFMAs
            half8 bh1[2];
            #pragma unroll
            for (int kt = 0; kt < 2; ++kt)
                bh1[kt] = *(const half8*)&h1p[pr1][kt * 512 + l8];
            #pragma unroll
            for (int j = 0; j < 2; ++j)
                #pragma unroll
                for (int kt = 0; kt < 2; ++kt)
                    acc1[j] = __builtin_amdgcn_mfma_f32_16x16x32_f16(
                                  A1[j][kt + 2], bh1[kt], acc1[j], 0, 0, 0);
        }

        // (5) gates
        if (doL0 && doL1) {
            floatx4 a4[4] = {acc0[0], acc0[1], acc1[0], acc1[1]};
            float   cc[4] = {c0[0], c0[1], c1[0], c1[1]};
            _Float16* pl[4] = {h0p[pr1], h0p[pr1], h1p[pr], h1p[pr]};
            int offs[4] = {hwr[0], hwr[1], hwr[0], hwr[1]};
            gate_batch<4>(a4, cc, pl, offs);
            c0[0] = cc[0]; c0[1] = cc[1]; c1[0] = cc[2]; c1[1] = cc[3];
        } else if (doL0) {
            floatx4 a2[2] = {acc0[0], acc0[1]};
            _Float16* pl[2] = {h0p[pr1], h0p[pr1]};
            int offs[2] = {hwr[0], hwr[1]};
            gate_batch<2>(a2, c0, pl, offs);
        } else {
            floatx4 a2[2] = {acc1[0], acc1[1]};
            _Float16* pl[2] = {h1p[pr], h1p[pr]};
            int offs[2] = {hwr[0], hwr[1]};
            gate_batch<2>(a2, c1, pl, offs);
        }

        // (6) x staging, then barrier
        if (p <= 25)
            xb[pr][xstg] = xone ? (_Float16)1.0f : (_Float16)xn;
        __syncthreads();
    }

    // ---- epilogue: out = h1(27) @ Wlin^T + blin ----
    wlin_s[tid] = Wlin[tid];
    if (tid < 128) wlin_s[512 + tid] = Wlin[512 + tid];
    if (tid < 10)  blin_s[tid] = blin[tid];
    __syncthreads();
    if (tid < 160) {
        int b = tid / 10, o = tid - b * 10;
        float a = blin_s[o];
        #pragma unroll 8
        for (int uu = 0; uu < 64; ++uu) {
            float hv = (float)h1p[1][(uu >> 5) * 512 + (((uu >> 3) & 3) * 16 + b) * 8 + (uu & 7)];
            a += wlin_s[o * 64 + uu] * hv;
        }
        out[(blockIdx.x * 16 + b) * 10 + o] = a;
    }
}

extern "C" void kernel_launch(void* const* d_in, const int* in_sizes, int n_in,
                              void* d_out, int out_size, void* d_ws, size_t ws_size,
                              hipStream_t stream) {
    const float* x    = (const float*)d_in[0];
    const float* Wih0 = (const float*)d_in[1];
    const float* Whh0 = (const float*)d_in[2];
    const float* bih0 = (const float*)d_in[3];
    const float* bhh0 = (const float*)d_in[4];
    const float* Wih1 = (const float*)d_in[5];
    const float* Whh1 = (const float*)d_in[6];
    const float* bih1 = (const float*)d_in[7];
    const float* bhh1 = (const float*)d_in[8];
    const float* Wlin = (const float*)d_in[9];
    const float* blin = (const float*)d_in[10];
    float* out = (float*)d_out;

    _Float16* wA    = (_Float16*)d_ws;
    float*    wBias = (float*)((char*)d_ws + WS_BIAS_OFF);

    prep_kernel<<<225, 256, 0, stream>>>(Wih0, Whh0, bih0, bhh0,
                                         Wih1, Whh1, bih1, bhh1, wA, wBias);
    lstm_mfma<<<1024, dim3(64, 8), 0, stream>>>(x, wA, wBias, Wlin, blin, out);
}

// Round 8
// 172.764 us; speedup vs baseline: 2.5739x; 2.5739x over previous
//
#include <hip/hip_runtime.h>

// --- MFMA fp16 LSTM, Round 19: program-order anti-phased n-halves ---
// r12 baseline (95.6us, 29 phases): 512-thr blocks, 2/CU. Invariant r12-r18:
// phase ~8k cyc, VALUBusy ~51-53% regardless of waves/SIMD (r17: half the
// waves, same time) -> not issue contention; waves traverse read-burst ->
// MFMA -> gate-burst in LOCKSTEP, so LDS (~3.3k/CU) and VALU (~4.2k/SIMD)
// phases alternate instead of overlapping. Scheduler desync null (r15);
// 4 barrier domains infeasible (r18: A-frags 56 VGPR x 32 waves > 512KB RF,
// compiler rematerialized A from HBM -> 358us).
// r19: deterministic anti-phase INSIDE the barrier window: waves w<4 process
// n-half 0 then 1; waves w>=4 process 1 then 0 (one of each per SIMD). Each
// pass = {reads, L0+L1 MFMAs, gates} for one n-half; B-group's LDS bursts
// land in A-group's gate bursts by program order. Zero extra barriers.
// Also: per-pass regs indexed by compile-time pass (no runtime-idx scratch);
// constant 1.0 bias row of xb written once at init (kills per-phase selects).
// Phase p: layer1(t=p) reads h0(p),h1(p-1); layer0(t=p+1) reads x(p+1),h0(p);
// 29 barriers. Weights pre-scaled (i/f/o by -log2e, g by +2log2e) -> bare
// exp2; gate math = verified 7-trans form. Planes frag-linear.

typedef _Float16 half8 __attribute__((ext_vector_type(8)));
typedef float floatx4 __attribute__((ext_vector_type(4)));

#define NFRAG 112
#define WS_BIAS_OFF (NFRAG * 1024)
#define K2 2.8853900817779268f      // 2*log2(e)

#if __has_builtin(__builtin_amdgcn_exp2f)
#define EXP2(v) __builtin_amdgcn_exp2f(v)
#else
#define EXP2(v) __expf(0.6931471805599453f * (v))
#endif
#define RCP(v) __builtin_amdgcn_rcpf(v)

__global__ void prep_kernel(const float* __restrict__ Wih0, const float* __restrict__ Whh0,
                            const float* __restrict__ bih0, const float* __restrict__ bhh0,
                            const float* __restrict__ Wih1, const float* __restrict__ Whh1,
                            const float* __restrict__ bih1, const float* __restrict__ bhh1,
                            _Float16* __restrict__ wA, float* __restrict__ wBias) {
    int idx = blockIdx.x * blockDim.x + threadIdx.x;
    if (idx < NFRAG * 512) {
        int f = idx >> 9, slot = idx & 511;
        int lane = slot >> 3, j = slot & 7;
        int mt, kt, layer;
        if (f < 48) { layer = 0; mt = f / 3; kt = f % 3; }
        else        { layer = 1; int f2 = f - 48; mt = f2 >> 2; kt = f2 & 3; }
        int m = mt * 16 + (lane & 15);
        int k = kt * 32 + (lane >> 4) * 8 + j;
        int u = m >> 2, g = m & 3;
        int row = g * 64 + u;
        float v;
        if (layer == 0) {
            if (k < 28)       v = Wih0[row * 28 + k];
            else if (k == 28) v = bih0[row] + bhh0[row];
            else if (k < 32)  v = 0.f;
            else              v = Whh0[row * 64 + (k - 32)];
        } else {
            if (k < 64)       v = Wih1[row * 64 + k];
            else              v = Whh1[row * 64 + (k - 64)];
        }
        float s = (g == 2) ? K2 : -1.4426950408889634f;
        wA[idx] = (_Float16)(v * s);
    } else if (idx < NFRAG * 512 + 256) {
        int m = idx - NFRAG * 512;
        int g = m & 3;
        int row = g * 64 + (m >> 2);
        float s = (g == 2) ? K2 : -1.4426950408889634f;
        wBias[m] = (bih1[row] + bhh1[row]) * s;
    }
}

// Breadth-first N-tile gate batch on PRE-SCALED accs (r12-verified form).
// cn = [c*pg*pi + (eg-1)*pf] / (pf*pg*pi)  (1 rcp); h = (ec-1)/(ec*po+po).
template <int N>
__device__ __forceinline__ void gate_batch(const floatx4* acc, float* c,
                                           _Float16* const* planes, const int* offs) {
    float ei[N], ef[N], eg[N], eo[N];
    #pragma unroll
    for (int i = 0; i < N; ++i) {
        floatx4 a = acc[i];
        ei[i] = EXP2(a[0]);
        ef[i] = EXP2(a[1]);
        eg[i] = EXP2(a[2]);
        eo[i] = EXP2(a[3]);
    }
    float num[N], rd[N], po[N];
    #pragma unroll
    for (int i = 0; i < N; ++i) {
        float pi = 1.0f + ei[i];
        float pf = 1.0f + ef[i];
        float pg = 1.0f + eg[i];
        po[i] = 1.0f + eo[i];
        float m = pg * pi;
        num[i] = c[i] * m + (eg[i] - 1.0f) * pf;
        rd[i]  = RCP(pf * m);
    }
    float ec[N];
    #pragma unroll
    for (int i = 0; i < N; ++i) {
        float cn = num[i] * rd[i];
        c[i] = cn;
        ec[i] = EXP2(K2 * cn);
    }
    #pragma unroll
    for (int i = 0; i < N; ++i) {
        float r2 = RCP(ec[i] * po[i] + po[i]);
        planes[i][offs[i]] = (_Float16)((ec[i] - 1.0f) * r2);
    }
}

__launch_bounds__(512, 4)
__global__ void lstm_mfma(const float* __restrict__ x,
                          const _Float16* __restrict__ wA,
                          const float* __restrict__ wBias,
                          const float* __restrict__ Wlin, const float* __restrict__ blin,
                          float* __restrict__ out) {
    __shared__ __align__(16) _Float16 h0p[2][2048];  // [parity][frag-linear]
    __shared__ __align__(16) _Float16 h1p[2][2048];
    __shared__ __align__(16) _Float16 xb[2][1024];
    __shared__ float wlin_s[640];
    __shared__ float blin_s[10];

    const int lane = threadIdx.x;
    const int w    = threadIdx.y;      // 0..7
    const int tid  = w * 64 + lane;
    const int quad = lane >> 4;
    const int col  = lane & 15;
    const int l8   = lane * 8;
    const int nord = (w >> 2) & 1;     // n-half order group: one of each per SIMD

    // ---- A fragments: wave owns m-tiles MT = 2w+j, units u = MT*4+quad ----
    half8 A0[2][3], A1[2][4];
    floatx4 bias1[2];
    int hwr0[2];
    #pragma unroll
    for (int j = 0; j < 2; ++j) {
        const int MT = 2 * w + j;
        #pragma unroll
        for (int kt = 0; kt < 3; ++kt)
            A0[j][kt] = *(const half8*)(wA + (MT * 3 + kt) * 512 + l8);
        #pragma unroll
        for (int kt = 0; kt < 4; ++kt)
            A1[j][kt] = *(const half8*)(wA + (48 + MT * 4 + kt) * 512 + l8);
        const int u = MT * 4 + quad;
        bias1[j] = *(const floatx4*)(wBias + u * 4);
        hwr0[j] = (u >> 5) * 512 + (((u >> 3) & 3) * 16 + col) * 8 + (u & 7);
    }

    // ---- x staging: thread covers b = tid>>5 and b+16, k = tid&31 ----
    const int ks = tid & 31;
    const bool xvalid = ks < 28;
    const int xbi = tid >> 5;          // 0..15
    const float* xg = x + (blockIdx.x * 32 + xbi) * 784 + ks;
    const int xstg = ((ks >> 3) * 16 + xbi) * 8 + (ks & 7);   // +512 for n-half 1

    // ---- init: zero h(-1) planes; stage x(0); constant rows to BOTH parities ----
    {
        ((int*)&h0p[1][0])[tid * 2 + 0] = 0;
        ((int*)&h0p[1][0])[tid * 2 + 1] = 0;
        ((int*)&h1p[1][0])[tid * 2 + 0] = 0;
        ((int*)&h1p[1][0])[tid * 2 + 1] = 0;
        float xv0 = xvalid ? xg[0] : 0.f;
        float xv1 = xvalid ? xg[16 * 784] : 0.f;
        _Float16 cpad = (ks == 28) ? (_Float16)1.0f : (_Float16)0.0f;
        xb[0][xstg]       = xvalid ? (_Float16)xv0 : cpad;
        xb[0][xstg + 512] = xvalid ? (_Float16)xv1 : cpad;
        xb[1][xstg]       = cpad;      // k>=28 rows are t-invariant
        xb[1][xstg + 512] = cpad;
    }
    __syncthreads();

    float c0[2][2] = {{0.f, 0.f}, {0.f, 0.f}};   // [pass][j]
    float c1[2][2] = {{0.f, 0.f}, {0.f, 0.f}};

    for (int p = -1; p <= 27; ++p) {
        const int pr  = p & 1;
        const int pr1 = pr ^ 1;
        const bool doL0 = (p < 27);
        const bool doL1 = (p >= 0);

        // (1) global prefetch x(p+2)
        float xn0 = 0.f, xn1 = 0.f;
        if (p <= 25 && xvalid) {
            xn0 = xg[(p + 2) * 28];
            xn1 = xg[16 * 784 + (p + 2) * 28];
        }

        // (2) two anti-phased passes: group nord=0 does n0,n1; nord=1 does n1,n0
        #pragma unroll
        for (int pass = 0; pass < 2; ++pass) {
            const int in = nord ^ pass;
            const int hb = in << 10;

            half8 bx, bh0[2];
            if (doL0) bx = *(const half8*)&xb[pr1][(in << 9) + l8];
            #pragma unroll
            for (int kt = 0; kt < 2; ++kt)
                bh0[kt] = *(const half8*)&h0p[pr][hb + kt * 512 + l8];

            floatx4 acc0[2], acc1[2];
            if (doL0) {
                #pragma unroll
                for (int j = 0; j < 2; ++j) {
                    acc0[j] = __builtin_amdgcn_mfma_f32_16x16x32_f16(
                                  A0[j][0], bx, (floatx4){0.f, 0.f, 0.f, 0.f}, 0, 0, 0);
                    #pragma unroll
                    for (int kt = 0; kt < 2; ++kt)
                        acc0[j] = __builtin_amdgcn_mfma_f32_16x16x32_f16(
                                      A0[j][kt + 1], bh0[kt], acc0[j], 0, 0, 0);
                }
            }
            if (doL1) {
                #pragma unroll
                for (int j = 0; j < 2; ++j) {
                    acc1[j] = bias1[j];
                    #pragma unroll
                    for (int kt = 0; kt < 2; ++kt)
                        acc1[j] = __builtin_amdgcn_mfma_f32_16x16x32_f16(
                                      A1[j][kt], bh0[kt], acc1[j], 0, 0, 0);
                }
                half8 bh1[2];
                #pragma unroll
                for (int kt = 0; kt < 2; ++kt)
                    bh1[kt] = *(const half8*)&h1p[pr1][hb + kt * 512 + l8];
                #pragma unroll
                for (int j = 0; j < 2; ++j)
                    #pragma unroll
                    for (int kt = 0; kt < 2; ++kt)
                        acc1[j] = __builtin_amdgcn_mfma_f32_16x16x32_f16(
                                      A1[j][kt + 2], bh1[kt], acc1[j], 0, 0, 0);
            }

            const int offA = hwr0[0] + hb;
            const int offB = hwr0[1] + hb;
            if (doL0 && doL1) {
                floatx4 a4[4] = {acc0[0], acc0[1], acc1[0], acc1[1]};
                float   cc[4] = {c0[pass][0], c0[pass][1], c1[pass][0], c1[pass][1]};
                _Float16* pl[4] = {h0p[pr1], h0p[pr1], h1p[pr], h1p[pr]};
                int offs[4] = {offA, offB, offA, offB};
                gate_batch<4>(a4, cc, pl, offs);
                c0[pass][0] = cc[0]; c0[pass][1] = cc[1];
                c1[pass][0] = cc[2]; c1[pass][1] = cc[3];
            } else if (doL0) {
                floatx4 a2[2] = {acc0[0], acc0[1]};
                _Float16* pl[2] = {h0p[pr1], h0p[pr1]};
                int offs[2] = {offA, offB};
                gate_batch<2>(a2, c0[pass], pl, offs);
            } else {
                floatx4 a2[2] = {acc1[0], acc1[1]};
                _Float16* pl[2] = {h1p[pr], h1p[pr]};
                int offs[2] = {offA, offB};
                gate_batch<2>(a2, c1[pass], pl, offs);
            }
        }

        // (3) x staging (valid lanes only; constant rows pre-written), barrier
        if (p <= 25 && xvalid) {
            xb[pr][xstg]       = (_Float16)xn0;
            xb[pr][xstg + 512] = (_Float16)xn1;
        }
        __syncthreads();
    }

    // ---- epilogue: out = h1(27) @ Wlin^T + blin ----
    wlin_s[tid] = Wlin[tid];
    if (tid < 128) wlin_s[512 + tid] = Wlin[512 + tid];
    if (tid < 10)  blin_s[tid] = blin[tid];
    __syncthreads();
    if (tid < 320) {
        int b = tid / 10, o = tid - b * 10;
        float a = blin_s[o];
        #pragma unroll 8
        for (int uu = 0; uu < 64; ++uu) {
            float hv = (float)h1p[1][((b >> 4) * 2 + (uu >> 5)) * 512 + (((uu >> 3) & 3) * 16 + (b & 15)) * 8 + (uu & 7)];
            a += wlin_s[o * 64 + uu] * hv;
        }
        out[(blockIdx.x * 32 + b) * 10 + o] = a;
    }
}

extern "C" void kernel_launch(void* const* d_in, const int* in_sizes, int n_in,
                              void* d_out, int out_size, void* d_ws, size_t ws_size,
                              hipStream_t stream) {
    const float* x    = (const float*)d_in[0];
    const float* Wih0 = (const float*)d_in[1];
    const float* Whh0 = (const float*)d_in[2];
    const float* bih0 = (const float*)d_in[3];
    const float* bhh0 = (const float*)d_in[4];
    const float* Wih1 = (const float*)d_in[5];
    const float* Whh1 = (const float*)d_in[6];
    const float* bih1 = (const float*)d_in[7];
    const float* bhh1 = (const float*)d_in[8];
    const float* Wlin = (const float*)d_in[9];
    const float* blin = (const float*)d_in[10];
    float* out = (float*)d_out;

    _Float16* wA    = (_Float16*)d_ws;
    float*    wBias = (float*)((char*)d_ws + WS_BIAS_OFF);

    prep_kernel<<<225, 256, 0, stream>>>(Wih0, Whh0, bih0, bhh0,
                                         Wih1, Whh1, bih1, bhh1, wA, wBias);
    lstm_mfma<<<512, dim3(64, 8), 0, stream>>>(x, wA, wBias, Wlin, blin, out);
}